// Round 25
// baseline (190.708 us; speedup 1.0000x reference)
//
#include <hip/hip_runtime.h>
#include <hip/hip_bf16.h>
#include <math.h>

#define B_  4
#define T_  2048
#define D_  1024
#define H_  16
#define HD_ 64
#define U_  38
#define M_  (B_*T_)   // 8192
#define NCB_ 8        // 256-j chunk-blocks per head (post block-reduce)
#define NC_ 64        // candidate slots per (b,h)

typedef __attribute__((ext_vector_type(8))) short bf16x8;
typedef __attribute__((ext_vector_type(4))) float f32x4;

__device__ __forceinline__ short f2b(float f) {
    __hip_bfloat16 b = __float2bfloat16(f);
    return *(short*)&b;
}
__device__ __forceinline__ float b2f(short s) {
    __hip_bfloat16 b = *(__hip_bfloat16*)&s;
    return __bfloat162float(b);
}
__device__ __forceinline__ unsigned pack2(float lo, float hi) {
    unsigned a = (unsigned short)f2b(lo);
    unsigned b = ((unsigned)(unsigned short)f2b(hi)) << 16;
    return a | b;
}

__device__ __forceinline__ void gload16(const void* g, void* l) {
    __builtin_amdgcn_global_load_lds(
        (const __attribute__((address_space(1))) unsigned int*)g,
        (__attribute__((address_space(3))) unsigned int*)l,
        16, 0, 0);
}

// Wave-level exact top-38 (lower-row-index tie-break), ascending-t emission
// into LDS idx/slot arrays. Executed by ONE 64-lane wave; deterministic.
__device__ __forceinline__ void wave_topk38(
    const float* __restrict__ cnorm, const int* __restrict__ cand,
    int g, int lane, int* sidx_lds, int* slot_lds)
{
    if (lane < 48) { sidx_lds[lane] = 0; if (slot_lds) slot_lds[lane] = 0; }
    float v = cnorm[g * NC_ + lane];
    int c = cand[g * NC_ + lane];
    int tt = (c < 0) ? (1 << 30) : c;
    if (c < 0) v = -3e38f;
    bool fl = false;
    for (int it = 0; it < U_; ++it) {
        float bv = v; int bt = tt; int bs = lane;
        for (int off = 32; off; off >>= 1) {
            float ov = __shfl_xor(bv, off);
            int ot = __shfl_xor(bt, off);
            int os = __shfl_xor(bs, off);
            if (ov > bv || (ov == bv && ot < bt)) { bv = ov; bt = ot; bs = os; }
        }
        if (bs == lane) { v = -3e38f; fl = true; }
    }
    unsigned long long bm = __ballot(fl);
    unsigned long long lowmask = ((unsigned long long)1 << lane) - 1;
    if (fl) {
        int p = __popcll(bm & lowmask);
        sidx_lds[p] = tt;
        if (slot_lds) slot_lds[p] = lane;
    }
}

// ---------------------------------------------------------------------------
// Fused conversions + output bias-fill.
// bid < 8192: x -> xh. bid < 12288: weight transposes (short4 stores).
// else: out = bo.
// ---------------------------------------------------------------------------
__global__ __launch_bounds__(256) void conv_fused(
    const float* __restrict__ x,
    const float* __restrict__ Wq, const float* __restrict__ Wk,
    const float* __restrict__ Wv, const float* __restrict__ Wo,
    const float* __restrict__ bo,
    short* __restrict__ xh,
    short* __restrict__ wq2, short* __restrict__ wkvt, short* __restrict__ wot,
    float* __restrict__ out)
{
    __shared__ float tile[32][33];
    const int bid = blockIdx.x;
    if (bid < 8192) {
        const size_t i = ((size_t)bid * 256 + threadIdx.x) * 4;
        float4 v = *(const float4*)(x + i);
        short4 h;
        h.x = f2b(v.x); h.y = f2b(v.y); h.z = f2b(v.z); h.w = f2b(v.w);
        *(short4*)(xh + i) = h;
        return;
    }
    if (bid >= 12288) {
        const size_t i = (size_t)(bid - 12288) * 256 + threadIdx.x;  // float4 idx
        float4 bv = *(const float4*)(bo + ((i & 255) << 2));
        *(float4*)(out + i * 4) = bv;
        return;
    }
    const int q = bid - 8192;
    const int which = q >> 10;
    const int by = (q & 1023) >> 5, bx = q & 31;
    const float* W = which == 0 ? Wq : (which == 1 ? Wk : (which == 2 ? Wv : Wo));
    const int k0 = by * 32, n0 = bx * 32;
    const int tx = threadIdx.x & 31, ty = threadIdx.x >> 5;
    #pragma unroll
    for (int r = ty; r < 32; r += 8)
        tile[r][tx] = W[(size_t)(k0 + r) * D_ + n0 + tx];   // tile[k][n]
    __syncthreads();
    const int rr = threadIdx.x >> 3;          // n_local
    const int kg = (threadIdx.x & 7) * 4;     // k_local base
    const float v0 = tile[kg + 0][rr], v1 = tile[kg + 1][rr];
    const float v2 = tile[kg + 2][rr], v3 = tile[kg + 3][rr];
    const size_t o = (size_t)(n0 + rr) * D_ + k0 + kg;
    if (which == 0) {
        short4 hi, lo;
        hi.x = f2b(v0); lo.x = f2b(v0 - b2f(hi.x));
        hi.y = f2b(v1); lo.y = f2b(v1 - b2f(hi.y));
        hi.z = f2b(v2); lo.z = f2b(v2 - b2f(hi.z));
        hi.w = f2b(v3); lo.w = f2b(v3 - b2f(hi.w));
        *(short4*)(wq2 + o) = hi;
        *(short4*)(wq2 + o + 1048576) = lo;
    } else {
        short4 p;
        p.x = f2b(v0); p.y = f2b(v1); p.z = f2b(v2); p.w = f2b(v3);
        if (which == 3) *(short4*)(wot + o) = p;
        else            *(short4*)(wkvt + (size_t)(which - 1) * D_ * D_ + o) = p;
    }
}

// ---------------------------------------------------------------------------
// FUSED projection GEMM, BK=128, 16x16x32 MFMA (r18/r20-proven: 63.4 us).
// ---------------------------------------------------------------------------
__global__ __launch_bounds__(256) void gemm_fused(
    const short* __restrict__ xh, const short* __restrict__ wq2,
    const short* __restrict__ wkvt,
    const float* __restrict__ bq, const float* __restrict__ bk,
    const float* __restrict__ bv,
    float* __restrict__ qnorm, short* __restrict__ kb, short* __restrict__ vt)
{
    __shared__ short As[128 * 128];
    __shared__ short Bs[128 * 128];
    const int bid = blockIdx.x;
    const bool isQ = bid < 512;
    const int tid = threadIdx.x, wid = tid >> 6, lane = tid & 63;
    const int l15 = lane & 15, gr = lane >> 4;
    const int lb = isQ ? bid : bid - 512;
    const int m0 = (lb & 63) * 128;
    const int n0 = (lb >> 6) * 128;
    const bool isK = !isQ && (n0 < D_);
    const int wr = (wid >> 1) * 64, wc = (wid & 1) * 64;

    f32x4 acc[4][4];
    #pragma unroll
    for (int i = 0; i < 4; ++i)
        #pragma unroll
        for (int j = 0; j < 4; ++j)
            acc[i][j] = (f32x4){0.f, 0.f, 0.f, 0.f};

    const short* Asrc = xh;
    const short* Bsrc = isQ ? wq2 : wkvt;

    for (int kt = 0; kt < 8; ++kt) {
        const int ka = kt * 128;
        #pragma unroll
        for (int i = 0; i < 8; ++i) {
            const int e = tid + i * 256;
            const int row = e >> 4;
            const int soff = ((e & 15) ^ (row & 15)) * 8;
            gload16(Asrc + (size_t)(m0 + row) * D_ + ka + soff,
                    (char*)As + i * 4096 + wid * 1024);
            gload16(Bsrc + (size_t)(n0 + row) * D_ + ka + soff,
                    (char*)Bs + i * 4096 + wid * 1024);
        }
        __syncthreads();
        #pragma unroll
        for (int ks = 0; ks < 4; ++ks) {
            bf16x8 a[4], b[4];
            #pragma unroll
            for (int i = 0; i < 4; ++i)
                a[i] = *(bf16x8*)((char*)As + (wr + i * 16 + l15) * 256
                                   + ((((ks << 2) | gr) ^ l15) * 16));
            #pragma unroll
            for (int j = 0; j < 4; ++j)
                b[j] = *(bf16x8*)((char*)Bs + (wc + j * 16 + l15) * 256
                                   + ((((ks << 2) | gr) ^ l15) * 16));
            if (isK) {
                #pragma unroll
                for (int i = 0; i < 4; ++i)
                    #pragma unroll
                    for (int j = 0; j < 4; ++j)
                        acc[i][j] = __builtin_amdgcn_mfma_f32_16x16x32_bf16(b[j], a[i], acc[i][j], 0, 0, 0);
            } else {
                #pragma unroll
                for (int i = 0; i < 4; ++i)
                    #pragma unroll
                    for (int j = 0; j < 4; ++j)
                        acc[i][j] = __builtin_amdgcn_mfma_f32_16x16x32_bf16(a[i], b[j], acc[i][j], 0, 0, 0);
            }
        }
        __syncthreads();
    }

    if (isQ) {
        const int h = (n0 + wc) >> 6;
        #pragma unroll
        for (int i = 0; i < 4; ++i)
            #pragma unroll
            for (int r = 0; r < 4; ++r) {
                int row = m0 + wr + i * 16 + gr * 4 + r;
                float s = 0.f;
                #pragma unroll
                for (int j = 0; j < 4; ++j) {
                    int col = n0 + wc + j * 16 + l15;
                    s += fabsf(acc[i][j][r] + bq[col]);
                }
                s += __shfl_xor(s, 1);
                s += __shfl_xor(s, 2);
                s += __shfl_xor(s, 4);
                s += __shfl_xor(s, 8);
                if (l15 == 0) {
                    int b = row >> 11, t = row & (T_ - 1);
                    qnorm[((size_t)b * H_ + h) * T_ + t] = s;
                }
            }
    } else if (isK) {
        #pragma unroll
        for (int i = 0; i < 4; ++i)
            #pragma unroll
            for (int j = 0; j < 4; ++j) {
                const int m = m0 + wr + i * 16 + l15;
                const int bb = m >> 11, t = m & (T_ - 1);
                const int n = n0 + wc + j * 16 + gr * 4;
                const int hh = n >> 6, dd = n & 63;
                float4 bias = *(const float4*)(bk + n);
                short4 pk;
                pk.x = f2b(acc[i][j][0] + bias.x);
                pk.y = f2b(acc[i][j][1] + bias.y);
                pk.z = f2b(acc[i][j][2] + bias.z);
                pk.w = f2b(acc[i][j][3] + bias.w);
                *(short4*)(kb + (((size_t)bb * H_ + hh) * T_ + t) * HD_ + dd) = pk;
            }
    } else {
        #pragma unroll
        for (int i = 0; i < 4; ++i)
            #pragma unroll
            for (int j = 0; j < 4; ++j) {
                const int col = n0 + wc + j * 16 + l15;   // in [1024,2048)
                const int rowb = m0 + wr + i * 16 + gr * 4;
                const int bb = rowb >> 11, t0 = rowb & (T_ - 1);
                const int cc2 = col - D_;
                const int hh = cc2 >> 6, dd = cc2 & 63;
                const float bias = bv[cc2];
                short4 pk;
                pk.x = f2b(acc[i][j][0] + bias);
                pk.y = f2b(acc[i][j][1] + bias);
                pk.z = f2b(acc[i][j][2] + bias);
                pk.w = f2b(acc[i][j][3] + bias);
                *(short4*)(vt + (((size_t)bb * H_ + hh) * HD_ + dd) * T_ + t0) = pk;
            }
    }
}

// ---------------------------------------------------------------------------
// Candidate selection per (b,h): top-<=64 rows by cheap norm, ascending-t.
// ---------------------------------------------------------------------------
__global__ __launch_bounds__(64) void cand_kernel(
    const float* __restrict__ qnorm, int* __restrict__ cand)
{
    const int g = blockIdx.x;
    const int lane = threadIdx.x;
    unsigned v[32];
    const float* src = qnorm + (size_t)g * T_ + lane * 32;
    #pragma unroll
    for (int i = 0; i < 32; i += 4) {
        float4 t = *(const float4*)(src + i);
        v[i] = __float_as_uint(t.x); v[i + 1] = __float_as_uint(t.y);
        v[i + 2] = __float_as_uint(t.z); v[i + 3] = __float_as_uint(t.w);
    }
    unsigned lo = 0, hi = 0x7F800000u;
    while (lo < hi) {
        unsigned mid = lo + ((hi - lo) >> 1);
        int c = 0;
        #pragma unroll
        for (int i = 0; i < 32; ++i) c += (v[i] >= mid) ? 1 : 0;
        #pragma unroll
        for (int off = 1; off < 64; off <<= 1) c += __shfl_xor(c, off);
        if (c <= NC_) hi = mid; else lo = mid + 1;
    }
    const unsigned tau = lo;
    int myc = 0;
    #pragma unroll
    for (int i = 0; i < 32; ++i) myc += (v[i] >= tau) ? 1 : 0;
    int inc = myc;
    for (int off = 1; off < 64; off <<= 1) {
        int n = __shfl_up(inc, off);
        if (lane >= off) inc += n;
    }
    const int total = __shfl(inc, 63);
    int pos = inc - myc;
    #pragma unroll
    for (int i = 0; i < 32; ++i)
        if (v[i] >= tau) cand[g * NC_ + pos++] = lane * 32 + i;
    for (int p = total + lane; p < NC_; p += 64)
        cand[g * NC_ + p] = -1;
}

// ---------------------------------------------------------------------------
// Recheck, K-split x2: 128 threads, wave w handles kt in [16w, 16w+16)
// (disjoint loads — no r11-style redundancy), partials combined via LDS
// (pad-20 rows, conflict-spread), wave 0 runs the unchanged epilogue.
// ---------------------------------------------------------------------------
__global__ __launch_bounds__(128) void recheck_kernel(
    const float* __restrict__ x,
    const short* __restrict__ wq2, const float* __restrict__ bq,
    const int* __restrict__ cand,
    float* __restrict__ cnorm, short* __restrict__ candq)
{
    __shared__ float lacc[128 * 20];
    const int blk = blockIdx.x;          // g*4 + rt
    const int g = blk >> 2, rt = blk & 3;
    const int b = g >> 4, h = g & 15;
    const int tid = threadIdx.x, w = tid >> 6, lane = tid & 63;
    const int l15 = lane & 15, gr = lane >> 4;

    const int aslot = rt * 16 + l15;
    int at = cand[g * NC_ + aslot];
    const float* xrow = x + ((size_t)b * T_ + (at < 0 ? 0 : at)) * D_;

    f32x4 acc[4];
    #pragma unroll
    for (int j = 0; j < 4; ++j) acc[j] = (f32x4){0.f, 0.f, 0.f, 0.f};

    const short* wqh = wq2;
    const short* wql = wq2 + 1048576;
    for (int kt = w * 16; kt < w * 16 + 16; ++kt) {
        const int k0 = kt * 32 + gr * 8;
        float4 xa = *(const float4*)(xrow + k0);
        float4 xb = *(const float4*)(xrow + k0 + 4);
        float xs[8] = {xa.x, xa.y, xa.z, xa.w, xb.x, xb.y, xb.z, xb.w};
        bf16x8 ah, al;
        #pragma unroll
        for (int e = 0; e < 8; ++e) {
            short hh = f2b(xs[e]);
            ah[e] = hh;
            al[e] = f2b(xs[e] - b2f(hh));
        }
        #pragma unroll
        for (int j = 0; j < 4; ++j) {
            const size_t wrow = (size_t)(h * HD_ + j * 16 + l15) * D_ + k0;
            bf16x8 bh = *(const bf16x8*)(wqh + wrow);
            bf16x8 bl = *(const bf16x8*)(wql + wrow);
            acc[j] = __builtin_amdgcn_mfma_f32_16x16x32_bf16(ah, bh, acc[j], 0, 0, 0);
            acc[j] = __builtin_amdgcn_mfma_f32_16x16x32_bf16(ah, bl, acc[j], 0, 0, 0);
            acc[j] = __builtin_amdgcn_mfma_f32_16x16x32_bf16(al, bh, acc[j], 0, 0, 0);
        }
    }

    #pragma unroll
    for (int j = 0; j < 4; ++j)
        *(f32x4*)&lacc[tid * 20 + j * 4] = acc[j];
    __syncthreads();
    if (w != 0) return;

    #pragma unroll
    for (int j = 0; j < 4; ++j) {
        f32x4 p0 = *(f32x4*)&lacc[lane * 20 + j * 4];
        f32x4 p1 = *(f32x4*)&lacc[(lane + 64) * 20 + j * 4];
        acc[j] = p0 + p1;
    }

    #pragma unroll
    for (int r = 0; r < 4; ++r) {
        const int slot = rt * 16 + gr * 4 + r;
        float s = 0.f;
        #pragma unroll
        for (int j = 0; j < 4; ++j) {
            const int col = j * 16 + l15;
            float val = acc[j][r] + bq[h * HD_ + col];
            candq[((size_t)g * NC_ + slot) * HD_ + col] = f2b(val);
            s += fabsf(val);
        }
        s += __shfl_xor(s, 1);
        s += __shfl_xor(s, 2);
        s += __shfl_xor(s, 4);
        s += __shfl_xor(s, 8);
        if (l15 == 0) {
            int ct = cand[g * NC_ + slot];
            cnorm[g * NC_ + slot] = (ct < 0) ? -3e38f : s;
        }
    }
}

// ---------------------------------------------------------------------------
// MFMA attention partials + in-block reduction; wave 0 recomputes the exact
// top-38 (deterministic) from cnorm/cand — removes the topk dispatch.
// ---------------------------------------------------------------------------
__global__ __launch_bounds__(256) void attn_part(
    const short* __restrict__ candq,
    const float* __restrict__ cnorm, const int* __restrict__ cand,
    const short* __restrict__ kb, const short* __restrict__ vt,
    float* __restrict__ pm, float* __restrict__ pl, float* __restrict__ po)
{
    __shared__ short qs[48 * 72];                       // 6,912 B
    __shared__ __align__(16) char shbuf[40448];         // pls (27,648) / red (40,448)
    __shared__ int sidx[48];
    __shared__ int ssl[48];
    short* pls  = (short*)shbuf;
    float* redo = (float*)shbuf;
    float* redm = (float*)(shbuf + 38912);
    float* redl = (float*)(shbuf + 39680);

    const int bid = blockIdx.x;
    const int g = bid & 63;
    const int c = bid >> 6;                             // 0..7
    const int tid = threadIdx.x, wid = tid >> 6, lane = tid & 63;
    const int l15 = lane & 15, gr = lane >> 4;
    const int j0w = (c * 4 + wid) * 64;

    if (wid == 0) wave_topk38(cnorm, cand, g, lane, sidx, ssl);
    __syncthreads();
    for (int e = tid; e < 48 * 16; e += 256) {
        int u = e >> 4, d4 = e & 15;
        short4 v = make_short4(0, 0, 0, 0);
        if (u < U_) {
            int slot = ssl[u];
            v = *(const short4*)(candq + ((size_t)g * NC_ + slot) * HD_ + d4 * 4);
        }
        *(short4*)&qs[u * 72 + d4 * 4] = v;
    }
    __syncthreads();

    bool skp[3];
    #pragma unroll
    for (int uf = 0; uf < 3; ++uf) {
        int mi = uf * 16 + 15; if (mi >= U_) mi = U_ - 1;
        skp[uf] = (sidx[mi] < j0w);                     // wave-uniform
    }

    int su[3];
    #pragma unroll
    for (int uf = 0; uf < 3; ++uf) su[uf] = sidx[uf * 16 + l15];

    f32x4 accs[3][4];
    #pragma unroll
    for (int uf = 0; uf < 3; ++uf)
        #pragma unroll
        for (int jf = 0; jf < 4; ++jf)
            accs[uf][jf] = (f32x4){0.f, 0.f, 0.f, 0.f};

    bf16x8 ka[4][2];
    #pragma unroll
    for (int jf = 0; jf < 4; ++jf)
        #pragma unroll
        for (int ks = 0; ks < 2; ++ks)
            ka[jf][ks] = *(const bf16x8*)(kb + ((size_t)g * T_ + j0w + jf * 16 + l15) * HD_ + ks * 32 + gr * 8);

    #pragma unroll
    for (int uf = 0; uf < 3; ++uf) {
        if (!skp[uf]) {
            bf16x8 q0 = *(bf16x8*)&qs[(uf * 16 + l15) * 72 + gr * 8];
            bf16x8 q1 = *(bf16x8*)&qs[(uf * 16 + l15) * 72 + 32 + gr * 8];
            #pragma unroll
            for (int jf = 0; jf < 4; ++jf) {
                accs[uf][jf] = __builtin_amdgcn_mfma_f32_16x16x32_bf16(ka[jf][0], q0, accs[uf][jf], 0, 0, 0);
                accs[uf][jf] = __builtin_amdgcn_mfma_f32_16x16x32_bf16(ka[jf][1], q1, accs[uf][jf], 0, 0, 0);
            }
        }
    }

    short* pw = pls + wid * 48 * 72;
    #pragma unroll
    for (int uf = 0; uf < 3; ++uf) {
        if (skp[uf]) {
            if (gr == 0) {
                int u = uf * 16 + l15;
                redm[wid * 48 + u] = -1e30f;
                redl[wid * 48 + u] = 0.f;
            }
        } else {
            float mm = -3e38f;
            #pragma unroll
            for (int jf = 0; jf < 4; ++jf)
                #pragma unroll
                for (int r = 0; r < 4; ++r) {
                    int j = j0w + jf * 16 + gr * 4 + r;
                    float s = accs[uf][jf][r] * 0.125f;
                    s = (j <= su[uf]) ? s : -1e30f;
                    accs[uf][jf][r] = s;
                    mm = fmaxf(mm, s);
                }
            mm = fmaxf(mm, __shfl_xor(mm, 16));
            mm = fmaxf(mm, __shfl_xor(mm, 32));
            float ll = 0.f;
            #pragma unroll
            for (int jf = 0; jf < 4; ++jf)
                #pragma unroll
                for (int r = 0; r < 4; ++r) {
                    float e = __expf(accs[uf][jf][r] - mm);
                    accs[uf][jf][r] = e;
                    ll += e;
                }
            ll += __shfl_xor(ll, 16);
            ll += __shfl_xor(ll, 32);
            if (gr == 0) {
                int u = uf * 16 + l15;
                redm[wid * 48 + u] = mm;
                redl[wid * 48 + u] = ll;
            }
            #pragma unroll
            for (int jf = 0; jf < 4; ++jf) {
                uint2 wv;
                wv.x = pack2(accs[uf][jf][0], accs[uf][jf][1]);
                wv.y = pack2(accs[uf][jf][2], accs[uf][jf][3]);
                *(uint2*)&pw[(uf * 16 + l15) * 72 + jf * 16 + gr * 4] = wv;
            }
        }
    }

    bf16x8 va[4][2];
    #pragma unroll
    for (int df = 0; df < 4; ++df)
        #pragma unroll
        for (int ks = 0; ks < 2; ++ks)
            va[df][ks] = *(const bf16x8*)(vt + ((size_t)g * HD_ + df * 16 + l15) * T_ + j0w + ks * 32 + gr * 8);

    f32x4 acco[4][3];
    #pragma unroll
    for (int df = 0; df < 4; ++df)
        #pragma unroll
        for (int uf = 0; uf < 3; ++uf)
            acco[df][uf] = (f32x4){0.f, 0.f, 0.f, 0.f};
    #pragma unroll
    for (int uf = 0; uf < 3; ++uf) {
        if (!skp[uf]) {
            bf16x8 p0 = *(bf16x8*)&pw[(uf * 16 + l15) * 72 + gr * 8];
            bf16x8 p1 = *(bf16x8*)&pw[(uf * 16 + l15) * 72 + 32 + gr * 8];
            #pragma unroll
            for (int df = 0; df < 4; ++df) {
                acco[df][uf] = __builtin_amdgcn_mfma_f32_16x16x32_bf16(va[df][0], p0, acco[df][uf], 0, 0, 0);
                acco[df][uf] = __builtin_amdgcn_mfma_f32_16x16x32_bf16(va[df][1], p1, acco[df][uf], 0, 0, 0);
            }
        }
    }

    __syncthreads();

    #pragma unroll
    for (int df = 0; df < 4; ++df)
        #pragma unroll
        for (int uf = 0; uf < 3; ++uf) {
            int u = uf * 16 + l15;
            if (u < U_) {
                float4 o;
                o.x = acco[df][uf][0]; o.y = acco[df][uf][1];
                o.z = acco[df][uf][2]; o.w = acco[df][uf][3];
                *(float4*)&redo[((size_t)(wid * 38 + u)) * 64 + df * 16 + gr * 4] = o;
            }
        }
    __syncthreads();

    for (int e = tid; e < U_ * 64; e += 256) {
        int u = e >> 6, d = e & 63;
        float m0 = redm[u], m1 = redm[48 + u], m2 = redm[96 + u], m3 = redm[144 + u];
        float m = fmaxf(fmaxf(m0, m1), fmaxf(m2, m3));
        float e0 = __expf(m0 - m), e1 = __expf(m1 - m), e2 = __expf(m2 - m), e3 = __expf(m3 - m);
        float l = redl[u] * e0 + redl[48 + u] * e1 + redl[96 + u] * e2 + redl[144 + u] * e3;
        float o = redo[(size_t)u * 64 + d] * e0
                + redo[(size_t)(38 + u) * 64 + d] * e1
                + redo[(size_t)(76 + u) * 64 + d] * e2
                + redo[(size_t)(114 + u) * 64 + d] * e3;
        po[((size_t)(g * NCB_ + c) * U_ + u) * HD_ + d] = o;
        if (d == 0) {
            pm[(size_t)(g * NCB_ + c) * U_ + u] = m;
            pl[(size_t)(g * NCB_ + c) * U_ + u] = l;
        }
    }
}

// ---------------------------------------------------------------------------
// Output projection with fused chunk-combine. Grid (g, ny). Wave 0
// recomputes the top-38 row indices (identical to attn_part's).
// ---------------------------------------------------------------------------
__global__ __launch_bounds__(256) void oproj_kernel(
    const float* __restrict__ pm, const float* __restrict__ pl,
    const float* __restrict__ po,
    const float* __restrict__ cnorm, const int* __restrict__ cand,
    const short* __restrict__ wot, float* __restrict__ out)
{
    __shared__ short sel[48 * 72];
    __shared__ int st[48];
    __shared__ float swl[U_][NCB_];
    const int g = blockIdx.x;
    const int ny = blockIdx.y;
    const int b = g >> 4, h = g & 15;
    const int tid = threadIdx.x, w = tid >> 6, lane = tid & 63;
    const int l15 = lane & 15, gr = lane >> 4;

    if (w == 0) wave_topk38(cnorm, cand, g, lane, st, (int*)0);
    if (tid < U_) {
        float mc[NCB_], lc[NCB_];
        #pragma unroll
        for (int c = 0; c < NCB_; ++c) {
            mc[c] = pm[(size_t)(g * NCB_ + c) * U_ + tid];
            lc[c] = pl[(size_t)(g * NCB_ + c) * U_ + tid];
        }
        float m = -3e38f;
        #pragma unroll
        for (int c = 0; c < NCB_; ++c) m = fmaxf(m, mc[c]);
        float wv[NCB_], l = 0.f;
        #pragma unroll
        for (int c = 0; c < NCB_; ++c) { wv[c] = __expf(mc[c] - m); l += lc[c] * wv[c]; }
        float inv = 1.f / l;
        #pragma unroll
        for (int c = 0; c < NCB_; ++c) swl[tid][c] = wv[c] * inv;
    }
    for (int e = tid; e < 48 * 16; e += 256) {
        int u = e >> 4, d4 = e & 15;
        if (u >= U_) *(short4*)&sel[u * 72 + d4 * 4] = make_short4(0, 0, 0, 0);
    }
    __syncthreads();

    for (int e = tid; e < U_ * 64; e += 256) {
        int u = e >> 6, d = e & 63;
        float o = 0.f;
        #pragma unroll
        for (int c = 0; c < NCB_; ++c)
            o += po[((size_t)(g * NCB_ + c) * U_ + u) * HD_ + d] * swl[u][c];
        sel[u * 72 + d] = f2b(o);
    }
    __syncthreads();

    bf16x8 a[3][2];
    #pragma unroll
    for (int uf = 0; uf < 3; ++uf)
        #pragma unroll
        for (int ks = 0; ks < 2; ++ks)
            a[uf][ks] = *(bf16x8*)&sel[(uf * 16 + l15) * 72 + ks * 32 + gr * 8];

    for (int nf = 0; nf < 8; ++nf) {
        const int n0 = ny * 512 + w * 128 + nf * 16;
        bf16x8 bf[2];
        #pragma unroll
        for (int ks = 0; ks < 2; ++ks)
            bf[ks] = *(const bf16x8*)(wot + (size_t)(n0 + l15) * D_ + h * HD_ + ks * 32 + gr * 8);
        f32x4 acc[3];
        #pragma unroll
        for (int uf = 0; uf < 3; ++uf) {
            acc[uf] = (f32x4){0.f, 0.f, 0.f, 0.f};
            acc[uf] = __builtin_amdgcn_mfma_f32_16x16x32_bf16(a[uf][0], bf[0], acc[uf], 0, 0, 0);
            acc[uf] = __builtin_amdgcn_mfma_f32_16x16x32_bf16(a[uf][1], bf[1], acc[uf], 0, 0, 0);
        }
        #pragma unroll
        for (int uf = 0; uf < 3; ++uf)
            #pragma unroll
            for (int r = 0; r < 4; ++r) {
                int u = uf * 16 + gr * 4 + r;
                if (u < U_)
                    atomicAdd(out + ((size_t)b * T_ + st[u]) * D_ + n0 + l15, acc[uf][r]);
            }
    }
}

// ---------------------------------------------------------------------------
extern "C" void kernel_launch(void* const* d_in, const int* in_sizes, int n_in,
                              void* d_out, int out_size, void* d_ws, size_t ws_size,
                              hipStream_t stream)
{
    const float* x  = (const float*)d_in[0];
    const float* Wq = (const float*)d_in[1];
    const float* bq = (const float*)d_in[2];
    const float* Wk = (const float*)d_in[3];
    const float* bk = (const float*)d_in[4];
    const float* Wv = (const float*)d_in[5];
    const float* bv = (const float*)d_in[6];
    const float* Wo = (const float*)d_in[7];
    const float* bo = (const float*)d_in[8];
    float* out = (float*)d_out;

    char* ws = (char*)d_ws;
    short* xh    = (short*)(ws);                        // 16,777,216
    short* wq2   = (short*)(ws + 33554432);             //  4,194,304  [wh;wl]
    short* wkvt  = (short*)(ws + 37748736);             //  4,194,304
    short* kb    = (short*)(ws + 41943040);             // 16,777,216
    short* vt    = (short*)(ws + 58720256);             // 16,777,216
    float* qnorm = (float*)(ws + 75497472);             //    524,288
    int*   cand  = (int*)  (ws + 76660736);             //     16,384
    float* cnorm = (float*)(ws + 76697600);             //     16,384
    short* candq = (short*)(ws + 76750848);             //    524,288
    short* wot   = (short*)(ws + 77930496);             //  2,097,152  end 80,027,648
    // partials overlay xh / old-xl region (dead after gemm/recheck):
    float* po    = (float*)(ws);                        //  4,980,736
    float* pm    = (float*)(ws + 19922944);             //     77,824
    float* pl    = (float*)(ws + 20234240);             //     77,824

    conv_fused<<<8192 + 4096 + 8192, 256, 0, stream>>>(x, Wq, Wk, Wv, Wo, bo,
                                                       xh, wq2, wkvt, wot, out);
    gemm_fused<<<1536, 256, 0, stream>>>(xh, wq2, wkvt, bq, bk, bv, qnorm, kb, vt);
    cand_kernel<<<B_ * H_, 64, 0, stream>>>(qnorm, cand);
    recheck_kernel<<<B_ * H_ * 4, 128, 0, stream>>>(x, wq2, bq, cand, cnorm, candq);
    attn_part<<<64 * NCB_, 256, 0, stream>>>(candq, cnorm, cand, kb, vt, pm, pl, po);
    oproj_kernel<<<dim3(B_ * H_, 2), 256, 0, stream>>>(pm, pl, po, cnorm, cand, wot, out);
}

// Round 26
// 172.921 us; speedup vs baseline: 1.1029x; 1.1029x over previous
//
#include <hip/hip_runtime.h>
#include <hip/hip_bf16.h>
#include <math.h>

#define B_  4
#define T_  2048
#define D_  1024
#define H_  16
#define HD_ 64
#define U_  38
#define M_  (B_*T_)   // 8192
#define NCB_ 8        // 256-j chunk-blocks per head (post block-reduce)
#define NC_ 64        // candidate slots per (b,h)

typedef __attribute__((ext_vector_type(8))) short bf16x8;
typedef __attribute__((ext_vector_type(4))) float f32x4;

__device__ __forceinline__ short f2b(float f) {
    __hip_bfloat16 b = __float2bfloat16(f);
    return *(short*)&b;
}
__device__ __forceinline__ float b2f(short s) {
    __hip_bfloat16 b = *(__hip_bfloat16*)&s;
    return __bfloat162float(b);
}
__device__ __forceinline__ unsigned pack2(float lo, float hi) {
    unsigned a = (unsigned short)f2b(lo);
    unsigned b = ((unsigned)(unsigned short)f2b(hi)) << 16;
    return a | b;
}

__device__ __forceinline__ void gload16(const void* g, void* l) {
    __builtin_amdgcn_global_load_lds(
        (const __attribute__((address_space(1))) unsigned int*)g,
        (__attribute__((address_space(3))) unsigned int*)l,
        16, 0, 0);
}

// ---------------------------------------------------------------------------
// Fused conversions + output bias-fill.
// bid < 8192: x -> xh. bid < 12288: weight transposes (short4 stores).
// else: out = bo.
// ---------------------------------------------------------------------------
__global__ __launch_bounds__(256) void conv_fused(
    const float* __restrict__ x,
    const float* __restrict__ Wq, const float* __restrict__ Wk,
    const float* __restrict__ Wv, const float* __restrict__ Wo,
    const float* __restrict__ bo,
    short* __restrict__ xh,
    short* __restrict__ wq2, short* __restrict__ wkvt, short* __restrict__ wot,
    float* __restrict__ out)
{
    __shared__ float tile[32][33];
    const int bid = blockIdx.x;
    if (bid < 8192) {
        const size_t i = ((size_t)bid * 256 + threadIdx.x) * 4;
        float4 v = *(const float4*)(x + i);
        short4 h;
        h.x = f2b(v.x); h.y = f2b(v.y); h.z = f2b(v.z); h.w = f2b(v.w);
        *(short4*)(xh + i) = h;
        return;
    }
    if (bid >= 12288) {
        const size_t i = (size_t)(bid - 12288) * 256 + threadIdx.x;  // float4 idx
        float4 bv = *(const float4*)(bo + ((i & 255) << 2));
        *(float4*)(out + i * 4) = bv;
        return;
    }
    const int q = bid - 8192;
    const int which = q >> 10;
    const int by = (q & 1023) >> 5, bx = q & 31;
    const float* W = which == 0 ? Wq : (which == 1 ? Wk : (which == 2 ? Wv : Wo));
    const int k0 = by * 32, n0 = bx * 32;
    const int tx = threadIdx.x & 31, ty = threadIdx.x >> 5;
    #pragma unroll
    for (int r = ty; r < 32; r += 8)
        tile[r][tx] = W[(size_t)(k0 + r) * D_ + n0 + tx];   // tile[k][n]
    __syncthreads();
    const int rr = threadIdx.x >> 3;          // n_local
    const int kg = (threadIdx.x & 7) * 4;     // k_local base
    const float v0 = tile[kg + 0][rr], v1 = tile[kg + 1][rr];
    const float v2 = tile[kg + 2][rr], v3 = tile[kg + 3][rr];
    const size_t o = (size_t)(n0 + rr) * D_ + k0 + kg;
    if (which == 0) {
        short4 hi, lo;
        hi.x = f2b(v0); lo.x = f2b(v0 - b2f(hi.x));
        hi.y = f2b(v1); lo.y = f2b(v1 - b2f(hi.y));
        hi.z = f2b(v2); lo.z = f2b(v2 - b2f(hi.z));
        hi.w = f2b(v3); lo.w = f2b(v3 - b2f(hi.w));
        *(short4*)(wq2 + o) = hi;
        *(short4*)(wq2 + o + 1048576) = lo;
    } else {
        short4 p;
        p.x = f2b(v0); p.y = f2b(v1); p.z = f2b(v2); p.w = f2b(v3);
        if (which == 3) *(short4*)(wot + o) = p;
        else            *(short4*)(wkvt + (size_t)(which - 1) * D_ * D_ + o) = p;
    }
}

// ---------------------------------------------------------------------------
// FUSED projection GEMM, BK=128, 16x16x32 MFMA (r18/r20-proven: 63.4 us,
// 812 TF). All structural variants (BK, shape, swizzle, launch_bounds,
// pipelines, XCD remap) measured worse — this is the locked configuration.
// ---------------------------------------------------------------------------
__global__ __launch_bounds__(256) void gemm_fused(
    const short* __restrict__ xh, const short* __restrict__ wq2,
    const short* __restrict__ wkvt,
    const float* __restrict__ bq, const float* __restrict__ bk,
    const float* __restrict__ bv,
    float* __restrict__ qnorm, short* __restrict__ kb, short* __restrict__ vt)
{
    __shared__ short As[128 * 128];
    __shared__ short Bs[128 * 128];
    const int bid = blockIdx.x;
    const bool isQ = bid < 512;
    const int tid = threadIdx.x, wid = tid >> 6, lane = tid & 63;
    const int l15 = lane & 15, gr = lane >> 4;
    const int lb = isQ ? bid : bid - 512;
    const int m0 = (lb & 63) * 128;
    const int n0 = (lb >> 6) * 128;
    const bool isK = !isQ && (n0 < D_);
    const int wr = (wid >> 1) * 64, wc = (wid & 1) * 64;

    f32x4 acc[4][4];
    #pragma unroll
    for (int i = 0; i < 4; ++i)
        #pragma unroll
        for (int j = 0; j < 4; ++j)
            acc[i][j] = (f32x4){0.f, 0.f, 0.f, 0.f};

    const short* Asrc = xh;
    const short* Bsrc = isQ ? wq2 : wkvt;

    for (int kt = 0; kt < 8; ++kt) {
        const int ka = kt * 128;
        #pragma unroll
        for (int i = 0; i < 8; ++i) {
            const int e = tid + i * 256;
            const int row = e >> 4;
            const int soff = ((e & 15) ^ (row & 15)) * 8;
            gload16(Asrc + (size_t)(m0 + row) * D_ + ka + soff,
                    (char*)As + i * 4096 + wid * 1024);
            gload16(Bsrc + (size_t)(n0 + row) * D_ + ka + soff,
                    (char*)Bs + i * 4096 + wid * 1024);
        }
        __syncthreads();
        #pragma unroll
        for (int ks = 0; ks < 4; ++ks) {
            bf16x8 a[4], b[4];
            #pragma unroll
            for (int i = 0; i < 4; ++i)
                a[i] = *(bf16x8*)((char*)As + (wr + i * 16 + l15) * 256
                                   + ((((ks << 2) | gr) ^ l15) * 16));
            #pragma unroll
            for (int j = 0; j < 4; ++j)
                b[j] = *(bf16x8*)((char*)Bs + (wc + j * 16 + l15) * 256
                                   + ((((ks << 2) | gr) ^ l15) * 16));
            if (isK) {
                #pragma unroll
                for (int i = 0; i < 4; ++i)
                    #pragma unroll
                    for (int j = 0; j < 4; ++j)
                        acc[i][j] = __builtin_amdgcn_mfma_f32_16x16x32_bf16(b[j], a[i], acc[i][j], 0, 0, 0);
            } else {
                #pragma unroll
                for (int i = 0; i < 4; ++i)
                    #pragma unroll
                    for (int j = 0; j < 4; ++j)
                        acc[i][j] = __builtin_amdgcn_mfma_f32_16x16x32_bf16(a[i], b[j], acc[i][j], 0, 0, 0);
            }
        }
        __syncthreads();
    }

    if (isQ) {
        const int h = (n0 + wc) >> 6;
        #pragma unroll
        for (int i = 0; i < 4; ++i)
            #pragma unroll
            for (int r = 0; r < 4; ++r) {
                int row = m0 + wr + i * 16 + gr * 4 + r;
                float s = 0.f;
                #pragma unroll
                for (int j = 0; j < 4; ++j) {
                    int col = n0 + wc + j * 16 + l15;
                    s += fabsf(acc[i][j][r] + bq[col]);
                }
                s += __shfl_xor(s, 1);
                s += __shfl_xor(s, 2);
                s += __shfl_xor(s, 4);
                s += __shfl_xor(s, 8);
                if (l15 == 0) {
                    int b = row >> 11, t = row & (T_ - 1);
                    qnorm[((size_t)b * H_ + h) * T_ + t] = s;
                }
            }
    } else if (isK) {
        #pragma unroll
        for (int i = 0; i < 4; ++i)
            #pragma unroll
            for (int j = 0; j < 4; ++j) {
                const int m = m0 + wr + i * 16 + l15;
                const int bb = m >> 11, t = m & (T_ - 1);
                const int n = n0 + wc + j * 16 + gr * 4;
                const int hh = n >> 6, dd = n & 63;
                float4 bias = *(const float4*)(bk + n);
                short4 pk;
                pk.x = f2b(acc[i][j][0] + bias.x);
                pk.y = f2b(acc[i][j][1] + bias.y);
                pk.z = f2b(acc[i][j][2] + bias.z);
                pk.w = f2b(acc[i][j][3] + bias.w);
                *(short4*)(kb + (((size_t)bb * H_ + hh) * T_ + t) * HD_ + dd) = pk;
            }
    } else {
        #pragma unroll
        for (int i = 0; i < 4; ++i)
            #pragma unroll
            for (int j = 0; j < 4; ++j) {
                const int col = n0 + wc + j * 16 + l15;   // in [1024,2048)
                const int rowb = m0 + wr + i * 16 + gr * 4;
                const int bb = rowb >> 11, t0 = rowb & (T_ - 1);
                const int cc2 = col - D_;
                const int hh = cc2 >> 6, dd = cc2 & 63;
                const float bias = bv[cc2];
                short4 pk;
                pk.x = f2b(acc[i][j][0] + bias);
                pk.y = f2b(acc[i][j][1] + bias);
                pk.z = f2b(acc[i][j][2] + bias);
                pk.w = f2b(acc[i][j][3] + bias);
                *(short4*)(vt + (((size_t)bb * H_ + hh) * HD_ + dd) * T_ + t0) = pk;
            }
    }
}

// ---------------------------------------------------------------------------
// Candidate selection per (b,h): top-<=64 rows by cheap norm, ascending-t.
// ---------------------------------------------------------------------------
__global__ __launch_bounds__(64) void cand_kernel(
    const float* __restrict__ qnorm, int* __restrict__ cand)
{
    const int g = blockIdx.x;
    const int lane = threadIdx.x;
    unsigned v[32];
    const float* src = qnorm + (size_t)g * T_ + lane * 32;
    #pragma unroll
    for (int i = 0; i < 32; i += 4) {
        float4 t = *(const float4*)(src + i);
        v[i] = __float_as_uint(t.x); v[i + 1] = __float_as_uint(t.y);
        v[i + 2] = __float_as_uint(t.z); v[i + 3] = __float_as_uint(t.w);
    }
    unsigned lo = 0, hi = 0x7F800000u;
    while (lo < hi) {
        unsigned mid = lo + ((hi - lo) >> 1);
        int c = 0;
        #pragma unroll
        for (int i = 0; i < 32; ++i) c += (v[i] >= mid) ? 1 : 0;
        #pragma unroll
        for (int off = 1; off < 64; off <<= 1) c += __shfl_xor(c, off);
        if (c <= NC_) hi = mid; else lo = mid + 1;
    }
    const unsigned tau = lo;
    int myc = 0;
    #pragma unroll
    for (int i = 0; i < 32; ++i) myc += (v[i] >= tau) ? 1 : 0;
    int inc = myc;
    for (int off = 1; off < 64; off <<= 1) {
        int n = __shfl_up(inc, off);
        if (lane >= off) inc += n;
    }
    const int total = __shfl(inc, 63);
    int pos = inc - myc;
    #pragma unroll
    for (int i = 0; i < 32; ++i)
        if (v[i] >= tau) cand[g * NC_ + pos++] = lane * 32 + i;
    for (int p = total + lane; p < NC_; p += 64)
        cand[g * NC_ + p] = -1;
}

// ---------------------------------------------------------------------------
// Recheck: exact 3-product split-bf16 norms + bf16 q for the candidates.
// One wave per (g, 16-slot tile) — 256 independent blocks (proven form).
// ---------------------------------------------------------------------------
__global__ __launch_bounds__(64) void recheck_kernel(
    const float* __restrict__ x,
    const short* __restrict__ wq2, const float* __restrict__ bq,
    const int* __restrict__ cand,
    float* __restrict__ cnorm, short* __restrict__ candq)
{
    const int blk = blockIdx.x;          // g*4 + rt
    const int g = blk >> 2, rt = blk & 3;
    const int b = g >> 4, h = g & 15;
    const int lane = threadIdx.x, l15 = lane & 15, gr = lane >> 4;

    const int aslot = rt * 16 + l15;
    int at = cand[g * NC_ + aslot];
    const float* xrow = x + ((size_t)b * T_ + (at < 0 ? 0 : at)) * D_;

    f32x4 acc[4];
    #pragma unroll
    for (int j = 0; j < 4; ++j) acc[j] = (f32x4){0.f, 0.f, 0.f, 0.f};

    const short* wqh = wq2;
    const short* wql = wq2 + 1048576;
    for (int kt = 0; kt < 32; ++kt) {
        const int k0 = kt * 32 + gr * 8;
        float4 xa = *(const float4*)(xrow + k0);
        float4 xb = *(const float4*)(xrow + k0 + 4);
        float xs[8] = {xa.x, xa.y, xa.z, xa.w, xb.x, xb.y, xb.z, xb.w};
        bf16x8 ah, al;
        #pragma unroll
        for (int e = 0; e < 8; ++e) {
            short hh = f2b(xs[e]);
            ah[e] = hh;
            al[e] = f2b(xs[e] - b2f(hh));
        }
        #pragma unroll
        for (int j = 0; j < 4; ++j) {
            const size_t wrow = (size_t)(h * HD_ + j * 16 + l15) * D_ + k0;
            bf16x8 bh = *(const bf16x8*)(wqh + wrow);
            bf16x8 bl = *(const bf16x8*)(wql + wrow);
            acc[j] = __builtin_amdgcn_mfma_f32_16x16x32_bf16(ah, bh, acc[j], 0, 0, 0);
            acc[j] = __builtin_amdgcn_mfma_f32_16x16x32_bf16(ah, bl, acc[j], 0, 0, 0);
            acc[j] = __builtin_amdgcn_mfma_f32_16x16x32_bf16(al, bh, acc[j], 0, 0, 0);
        }
    }

    #pragma unroll
    for (int r = 0; r < 4; ++r) {
        const int slot = rt * 16 + gr * 4 + r;
        float s = 0.f;
        #pragma unroll
        for (int j = 0; j < 4; ++j) {
            const int col = j * 16 + l15;
            float val = acc[j][r] + bq[h * HD_ + col];
            candq[((size_t)g * NC_ + slot) * HD_ + col] = f2b(val);
            s += fabsf(val);
        }
        s += __shfl_xor(s, 1);
        s += __shfl_xor(s, 2);
        s += __shfl_xor(s, 4);
        s += __shfl_xor(s, 8);
        if (l15 == 0) {
            int ct = cand[g * NC_ + slot];
            cnorm[g * NC_ + slot] = (ct < 0) ? -3e38f : s;
        }
    }
}

// ---------------------------------------------------------------------------
// Exact top-38 among the 64 candidates, ascending-t emission.
// ---------------------------------------------------------------------------
__global__ __launch_bounds__(64) void topk38_kernel(
    const float* __restrict__ cnorm, const int* __restrict__ cand,
    int* __restrict__ idxb, int* __restrict__ slotb)
{
    const int g = blockIdx.x;
    const int lane = threadIdx.x;
    float v = cnorm[g * NC_ + lane];
    int c = cand[g * NC_ + lane];
    int tt = (c < 0) ? (1 << 30) : c;
    if (c < 0) v = -3e38f;
    bool fl = false;
    for (int it = 0; it < U_; ++it) {
        float bv = v; int bt = tt; int bs = lane;
        for (int off = 32; off; off >>= 1) {
            float ov = __shfl_xor(bv, off);
            int ot = __shfl_xor(bt, off);
            int os = __shfl_xor(bs, off);
            if (ov > bv || (ov == bv && ot < bt)) { bv = ov; bt = ot; bs = os; }
        }
        if (bs == lane) { v = -3e38f; fl = true; }
    }
    unsigned long long bm = __ballot(fl);
    unsigned long long lowmask = ((unsigned long long)1 << lane) - 1;
    if (fl) {
        int p = __popcll(bm & lowmask);
        idxb[g * U_ + p] = tt;
        slotb[g * 40 + p] = lane;
    }
}

// ---------------------------------------------------------------------------
// MFMA attention partials + in-block reduction; per-16-u-group causal skip.
// ---------------------------------------------------------------------------
__global__ __launch_bounds__(256) void attn_part(
    const short* __restrict__ candq, const int* __restrict__ slotb,
    const short* __restrict__ kb, const short* __restrict__ vt,
    const int* __restrict__ idxb,
    float* __restrict__ pm, float* __restrict__ pl, float* __restrict__ po)
{
    __shared__ short qs[48 * 72];                       // 6,912 B
    __shared__ __align__(16) char shbuf[40448];         // pls (27,648) / red (40,448)
    __shared__ int sidx[48];
    short* pls  = (short*)shbuf;
    float* redo = (float*)shbuf;
    float* redm = (float*)(shbuf + 38912);
    float* redl = (float*)(shbuf + 39680);

    const int bid = blockIdx.x;
    const int g = bid & 63;
    const int c = bid >> 6;                             // 0..7
    const int tid = threadIdx.x, wid = tid >> 6, lane = tid & 63;
    const int l15 = lane & 15, gr = lane >> 4;
    const int j0w = (c * 4 + wid) * 64;

    if (tid < 48) sidx[tid] = (tid < U_) ? idxb[g * U_ + tid] : 0;
    __syncthreads();
    for (int e = tid; e < 48 * 16; e += 256) {
        int u = e >> 4, d4 = e & 15;
        short4 v = make_short4(0, 0, 0, 0);
        if (u < U_) {
            int slot = slotb[g * 40 + u];
            v = *(const short4*)(candq + ((size_t)g * NC_ + slot) * HD_ + d4 * 4);
        }
        *(short4*)&qs[u * 72 + d4 * 4] = v;
    }
    __syncthreads();

    bool skp[3];
    #pragma unroll
    for (int uf = 0; uf < 3; ++uf) {
        int mi = uf * 16 + 15; if (mi >= U_) mi = U_ - 1;
        skp[uf] = (sidx[mi] < j0w);                     // wave-uniform
    }

    int su[3];
    #pragma unroll
    for (int uf = 0; uf < 3; ++uf) su[uf] = sidx[uf * 16 + l15];

    f32x4 accs[3][4];
    #pragma unroll
    for (int uf = 0; uf < 3; ++uf)
        #pragma unroll
        for (int jf = 0; jf < 4; ++jf)
            accs[uf][jf] = (f32x4){0.f, 0.f, 0.f, 0.f};

    bf16x8 ka[4][2];
    #pragma unroll
    for (int jf = 0; jf < 4; ++jf)
        #pragma unroll
        for (int ks = 0; ks < 2; ++ks)
            ka[jf][ks] = *(const bf16x8*)(kb + ((size_t)g * T_ + j0w + jf * 16 + l15) * HD_ + ks * 32 + gr * 8);

    #pragma unroll
    for (int uf = 0; uf < 3; ++uf) {
        if (!skp[uf]) {
            bf16x8 q0 = *(bf16x8*)&qs[(uf * 16 + l15) * 72 + gr * 8];
            bf16x8 q1 = *(bf16x8*)&qs[(uf * 16 + l15) * 72 + 32 + gr * 8];
            #pragma unroll
            for (int jf = 0; jf < 4; ++jf) {
                accs[uf][jf] = __builtin_amdgcn_mfma_f32_16x16x32_bf16(ka[jf][0], q0, accs[uf][jf], 0, 0, 0);
                accs[uf][jf] = __builtin_amdgcn_mfma_f32_16x16x32_bf16(ka[jf][1], q1, accs[uf][jf], 0, 0, 0);
            }
        }
    }

    short* pw = pls + wid * 48 * 72;
    #pragma unroll
    for (int uf = 0; uf < 3; ++uf) {
        if (skp[uf]) {
            if (gr == 0) {
                int u = uf * 16 + l15;
                redm[wid * 48 + u] = -1e30f;
                redl[wid * 48 + u] = 0.f;
            }
        } else {
            float mm = -3e38f;
            #pragma unroll
            for (int jf = 0; jf < 4; ++jf)
                #pragma unroll
                for (int r = 0; r < 4; ++r) {
                    int j = j0w + jf * 16 + gr * 4 + r;
                    float s = accs[uf][jf][r] * 0.125f;
                    s = (j <= su[uf]) ? s : -1e30f;
                    accs[uf][jf][r] = s;
                    mm = fmaxf(mm, s);
                }
            mm = fmaxf(mm, __shfl_xor(mm, 16));
            mm = fmaxf(mm, __shfl_xor(mm, 32));
            float ll = 0.f;
            #pragma unroll
            for (int jf = 0; jf < 4; ++jf)
                #pragma unroll
                for (int r = 0; r < 4; ++r) {
                    float e = __expf(accs[uf][jf][r] - mm);
                    accs[uf][jf][r] = e;
                    ll += e;
                }
            ll += __shfl_xor(ll, 16);
            ll += __shfl_xor(ll, 32);
            if (gr == 0) {
                int u = uf * 16 + l15;
                redm[wid * 48 + u] = mm;
                redl[wid * 48 + u] = ll;
            }
            #pragma unroll
            for (int jf = 0; jf < 4; ++jf) {
                uint2 wv;
                wv.x = pack2(accs[uf][jf][0], accs[uf][jf][1]);
                wv.y = pack2(accs[uf][jf][2], accs[uf][jf][3]);
                *(uint2*)&pw[(uf * 16 + l15) * 72 + jf * 16 + gr * 4] = wv;
            }
        }
    }

    bf16x8 va[4][2];
    #pragma unroll
    for (int df = 0; df < 4; ++df)
        #pragma unroll
        for (int ks = 0; ks < 2; ++ks)
            va[df][ks] = *(const bf16x8*)(vt + ((size_t)g * HD_ + df * 16 + l15) * T_ + j0w + ks * 32 + gr * 8);

    f32x4 acco[4][3];
    #pragma unroll
    for (int df = 0; df < 4; ++df)
        #pragma unroll
        for (int uf = 0; uf < 3; ++uf)
            acco[df][uf] = (f32x4){0.f, 0.f, 0.f, 0.f};
    #pragma unroll
    for (int uf = 0; uf < 3; ++uf) {
        if (!skp[uf]) {
            bf16x8 p0 = *(bf16x8*)&pw[(uf * 16 + l15) * 72 + gr * 8];
            bf16x8 p1 = *(bf16x8*)&pw[(uf * 16 + l15) * 72 + 32 + gr * 8];
            #pragma unroll
            for (int df = 0; df < 4; ++df) {
                acco[df][uf] = __builtin_amdgcn_mfma_f32_16x16x32_bf16(va[df][0], p0, acco[df][uf], 0, 0, 0);
                acco[df][uf] = __builtin_amdgcn_mfma_f32_16x16x32_bf16(va[df][1], p1, acco[df][uf], 0, 0, 0);
            }
        }
    }

    __syncthreads();

    #pragma unroll
    for (int df = 0; df < 4; ++df)
        #pragma unroll
        for (int uf = 0; uf < 3; ++uf) {
            int u = uf * 16 + l15;
            if (u < U_) {
                float4 o;
                o.x = acco[df][uf][0]; o.y = acco[df][uf][1];
                o.z = acco[df][uf][2]; o.w = acco[df][uf][3];
                *(float4*)&redo[((size_t)(wid * 38 + u)) * 64 + df * 16 + gr * 4] = o;
            }
        }
    __syncthreads();

    for (int e = tid; e < U_ * 64; e += 256) {
        int u = e >> 6, d = e & 63;
        float m0 = redm[u], m1 = redm[48 + u], m2 = redm[96 + u], m3 = redm[144 + u];
        float m = fmaxf(fmaxf(m0, m1), fmaxf(m2, m3));
        float e0 = __expf(m0 - m), e1 = __expf(m1 - m), e2 = __expf(m2 - m), e3 = __expf(m3 - m);
        float l = redl[u] * e0 + redl[48 + u] * e1 + redl[96 + u] * e2 + redl[144 + u] * e3;
        float o = redo[(size_t)u * 64 + d] * e0
                + redo[(size_t)(38 + u) * 64 + d] * e1
                + redo[(size_t)(76 + u) * 64 + d] * e2
                + redo[(size_t)(114 + u) * 64 + d] * e3;
        po[((size_t)(g * NCB_ + c) * U_ + u) * HD_ + d] = o;
        if (d == 0) {
            pm[(size_t)(g * NCB_ + c) * U_ + u] = m;
            pl[(size_t)(g * NCB_ + c) * U_ + u] = l;
        }
    }
}

// ---------------------------------------------------------------------------
// Output projection with fused chunk-combine. Grid (g, ny).
// ---------------------------------------------------------------------------
__global__ __launch_bounds__(256) void oproj_kernel(
    const float* __restrict__ pm, const float* __restrict__ pl,
    const float* __restrict__ po, const int* __restrict__ idxb,
    const short* __restrict__ wot, float* __restrict__ out)
{
    __shared__ short sel[48 * 72];
    __shared__ int st[48];
    __shared__ float swl[U_][NCB_];
    const int g = blockIdx.x;
    const int ny = blockIdx.y;
    const int b = g >> 4, h = g & 15;
    const int tid = threadIdx.x, w = tid >> 6, lane = tid & 63;
    const int l15 = lane & 15, gr = lane >> 4;

    if (tid < 48) st[tid] = (tid < U_) ? idxb[g * U_ + tid] : 0;
    if (tid < U_) {
        float mc[NCB_], lc[NCB_];
        #pragma unroll
        for (int c = 0; c < NCB_; ++c) {
            mc[c] = pm[(size_t)(g * NCB_ + c) * U_ + tid];
            lc[c] = pl[(size_t)(g * NCB_ + c) * U_ + tid];
        }
        float m = -3e38f;
        #pragma unroll
        for (int c = 0; c < NCB_; ++c) m = fmaxf(m, mc[c]);
        float wv[NCB_], l = 0.f;
        #pragma unroll
        for (int c = 0; c < NCB_; ++c) { wv[c] = __expf(mc[c] - m); l += lc[c] * wv[c]; }
        float inv = 1.f / l;
        #pragma unroll
        for (int c = 0; c < NCB_; ++c) swl[tid][c] = wv[c] * inv;
    }
    for (int e = tid; e < 48 * 16; e += 256) {
        int u = e >> 4, d4 = e & 15;
        if (u >= U_) *(short4*)&sel[u * 72 + d4 * 4] = make_short4(0, 0, 0, 0);
    }
    __syncthreads();

    for (int e = tid; e < U_ * 64; e += 256) {
        int u = e >> 6, d = e & 63;
        float o = 0.f;
        #pragma unroll
        for (int c = 0; c < NCB_; ++c)
            o += po[((size_t)(g * NCB_ + c) * U_ + u) * HD_ + d] * swl[u][c];
        sel[u * 72 + d] = f2b(o);
    }
    __syncthreads();

    bf16x8 a[3][2];
    #pragma unroll
    for (int uf = 0; uf < 3; ++uf)
        #pragma unroll
        for (int ks = 0; ks < 2; ++ks)
            a[uf][ks] = *(bf16x8*)&sel[(uf * 16 + l15) * 72 + ks * 32 + gr * 8];

    for (int nf = 0; nf < 8; ++nf) {
        const int n0 = ny * 512 + w * 128 + nf * 16;
        bf16x8 bf[2];
        #pragma unroll
        for (int ks = 0; ks < 2; ++ks)
            bf[ks] = *(const bf16x8*)(wot + (size_t)(n0 + l15) * D_ + h * HD_ + ks * 32 + gr * 8);
        f32x4 acc[3];
        #pragma unroll
        for (int uf = 0; uf < 3; ++uf) {
            acc[uf] = (f32x4){0.f, 0.f, 0.f, 0.f};
            acc[uf] = __builtin_amdgcn_mfma_f32_16x16x32_bf16(a[uf][0], bf[0], acc[uf], 0, 0, 0);
            acc[uf] = __builtin_amdgcn_mfma_f32_16x16x32_bf16(a[uf][1], bf[1], acc[uf], 0, 0, 0);
        }
        #pragma unroll
        for (int uf = 0; uf < 3; ++uf)
            #pragma unroll
            for (int r = 0; r < 4; ++r) {
                int u = uf * 16 + gr * 4 + r;
                if (u < U_)
                    atomicAdd(out + ((size_t)b * T_ + st[u]) * D_ + n0 + l15, acc[uf][r]);
            }
    }
}

// ---------------------------------------------------------------------------
extern "C" void kernel_launch(void* const* d_in, const int* in_sizes, int n_in,
                              void* d_out, int out_size, void* d_ws, size_t ws_size,
                              hipStream_t stream)
{
    const float* x  = (const float*)d_in[0];
    const float* Wq = (const float*)d_in[1];
    const float* bq = (const float*)d_in[2];
    const float* Wk = (const float*)d_in[3];
    const float* bk = (const float*)d_in[4];
    const float* Wv = (const float*)d_in[5];
    const float* bv = (const float*)d_in[6];
    const float* Wo = (const float*)d_in[7];
    const float* bo = (const float*)d_in[8];
    float* out = (float*)d_out;

    char* ws = (char*)d_ws;
    short* xh    = (short*)(ws);                        // 16,777,216
    short* wq2   = (short*)(ws + 33554432);             //  4,194,304  [wh;wl]
    short* wkvt  = (short*)(ws + 37748736);             //  4,194,304
    short* kb    = (short*)(ws + 41943040);             // 16,777,216
    short* vt    = (short*)(ws + 58720256);             // 16,777,216
    float* qnorm = (float*)(ws + 75497472);             //    524,288
    int*   idxb  = (int*)  (ws + 76021760);             //     16,384
    int*   cand  = (int*)  (ws + 76660736);             //     16,384
    float* cnorm = (float*)(ws + 76697600);             //     16,384
    int*   slotb = (int*)  (ws + 76734464);             //     16,384
    short* candq = (short*)(ws + 76750848);             //    524,288
    short* wot   = (short*)(ws + 77930496);             //  2,097,152  end 80,027,648
    // partials overlay xh / old-xl region (dead after gemm/recheck):
    float* po    = (float*)(ws);                        //  4,980,736
    float* pm    = (float*)(ws + 19922944);             //     77,824
    float* pl    = (float*)(ws + 20234240);             //     77,824

    conv_fused<<<8192 + 4096 + 8192, 256, 0, stream>>>(x, Wq, Wk, Wv, Wo, bo,
                                                       xh, wq2, wkvt, wot, out);
    gemm_fused<<<1536, 256, 0, stream>>>(xh, wq2, wkvt, bq, bk, bv, qnorm, kb, vt);
    cand_kernel<<<B_ * H_, 64, 0, stream>>>(qnorm, cand);
    recheck_kernel<<<B_ * H_ * 4, 64, 0, stream>>>(x, wq2, bq, cand, cnorm, candq);
    topk38_kernel<<<B_ * H_, 64, 0, stream>>>(cnorm, cand, idxb, slotb);
    attn_part<<<64 * NCB_, 256, 0, stream>>>(candq, slotb, kb, vt, idxb, pm, pl, po);
    oproj_kernel<<<dim3(B_ * H_, 2), 256, 0, stream>>>(pm, pl, po, idxb, wot, out);
}